// Round 1
// baseline (1451.535 us; speedup 1.0000x reference)
//
#include <hip/hip_runtime.h>
#include <math.h>

#define NN 100000
#define NE 1600000
#define NG 64

__device__ __forceinline__ float gelu_f(float x) {
    return 0.5f * x * (1.0f + erff(x * 0.7071067811865475f));
}

// ---------------- CSR build ----------------
__global__ void k_hist(const int* __restrict__ dstp, int* __restrict__ cnt) {
    int e = blockIdx.x * 256 + threadIdx.x;
    if (e < NE) atomicAdd(&cnt[dstp[e]], 1);
}

#define SB 1024
__global__ __launch_bounds__(SB) void k_scan1(const int* __restrict__ cnt, int* __restrict__ rowp,
                                              int* __restrict__ blksum) {
    __shared__ int s[SB];
    int tid = threadIdx.x;
    int i = blockIdx.x * SB + tid;
    int v = (i < NN) ? cnt[i] : 0;
    int run = v;
    s[tid] = v;
    __syncthreads();
    for (int off = 1; off < SB; off <<= 1) {
        int t = (tid >= off) ? s[tid - off] : 0;
        __syncthreads();
        run += t;
        s[tid] = run;
        __syncthreads();
    }
    if (i < NN) rowp[i] = run - v;            // exclusive within block
    if (tid == SB - 1) blksum[blockIdx.x] = run;
}

__global__ void k_scan2(const int* __restrict__ blksum, int* __restrict__ blkoff, int nb) {
    __shared__ int s[128];
    int tid = threadIdx.x;
    int v = (tid < nb) ? blksum[tid] : 0;
    int run = v;
    s[tid] = v;
    __syncthreads();
    for (int off = 1; off < 128; off <<= 1) {
        int t = (tid >= off) ? s[tid - off] : 0;
        __syncthreads();
        run += t;
        s[tid] = run;
        __syncthreads();
    }
    if (tid < nb) blkoff[tid] = run - v;
}

__global__ void k_scan3(int* __restrict__ rowp, const int* __restrict__ blkoff) {
    int i = blockIdx.x * 256 + threadIdx.x;
    if (i < NN) rowp[i] += blkoff[i >> 10];
    else if (i == NN) rowp[NN] = NE;
}

__global__ void k_scatter(const int* __restrict__ srcp, const int* __restrict__ dstp,
                          const int* __restrict__ rowp, int* __restrict__ fill,
                          int* __restrict__ cidx) {
    int e = blockIdx.x * 256 + threadIdx.x;
    if (e < NE) {
        int d = dstp[e];
        int pos = atomicAdd(&fill[d], 1);
        cidx[rowp[d] + pos] = srcp[e];
    }
}

// ---------------- mean-aggregate: one wave per node ----------------
__global__ __launch_bounds__(256) void k_agg(const float* __restrict__ xin, const int* __restrict__ rowp,
                                             const int* __restrict__ cidx, float* __restrict__ agg) {
    int node = (blockIdx.x * 256 + threadIdx.x) >> 6;
    int lane = threadIdx.x & 63;
    if (node >= NN) return;
    int beg = rowp[node], endp = rowp[node + 1];
    const float2* x2 = (const float2*)xin;
    float ax = 0.f, ay = 0.f;
    int e = beg;
    for (; e + 1 < endp; e += 2) {
        int s0 = cidx[e], s1 = cidx[e + 1];
        float2 v0 = x2[(size_t)s0 * 64 + lane];
        float2 v1 = x2[(size_t)s1 * 64 + lane];
        ax += v0.x + v1.x;
        ay += v0.y + v1.y;
    }
    if (e < endp) {
        int s0 = cidx[e];
        float2 v0 = x2[(size_t)s0 * 64 + lane];
        ax += v0.x;
        ay += v0.y;
    }
    float inv = 1.0f / fmaxf((float)(endp - beg), 1.0f);
    float2 r;
    r.x = ax * inv;
    r.y = ay * inv;
    ((float2*)agg)[(size_t)node * 64 + lane] = r;
}

// ---------------- fused SAGE layer: out = gelu(A1@W1 + b1 + A2@W2) ----------------
// 256 threads; block tile = 128 nodes x 128 cols; thread = 4 nodes x 16 cols.
// NOTE: `out` may alias A1 or A2 — safe because each row is read only by the 8
// lanes (same wave) that write it, and all k-loop loads precede epilogue stores.
__global__ __launch_bounds__(256) void k_sage(const float* A1, const float* __restrict__ W1,
                                              const float* __restrict__ b1, const float* A2,
                                              const float* __restrict__ W2, float* out) {
    const int t = threadIdx.x;
    const int cg = t & 7;
    const int ng = t >> 3;
    const int n0 = blockIdx.x * 128 + ng * 4;
    const int c0 = cg * 16;
    float acc[4][16];
#pragma unroll
    for (int i = 0; i < 4; ++i)
#pragma unroll
        for (int j = 0; j < 16; ++j) acc[i][j] = 0.f;
    const float *r1[4], *r2[4];
#pragma unroll
    for (int i = 0; i < 4; ++i) {
        int n = n0 + i;
        if (n >= NN) n = NN - 1;  // clamp loads; stores guarded below
        r1[i] = A1 + (size_t)n * 128;
        r2[i] = A2 + (size_t)n * 128;
    }
    for (int k = 0; k < 128; k += 4) {
        float4 a1[4], a2[4];
#pragma unroll
        for (int i = 0; i < 4; ++i) {
            a1[i] = *(const float4*)(r1[i] + k);
            a2[i] = *(const float4*)(r2[i] + k);
        }
#pragma unroll
        for (int kk = 0; kk < 4; ++kk) {
            float w1v[16], w2v[16];
            const float* w1p = W1 + (k + kk) * 128 + c0;
            const float* w2p = W2 + (k + kk) * 128 + c0;
            *(float4*)(w1v + 0)  = *(const float4*)(w1p + 0);
            *(float4*)(w1v + 4)  = *(const float4*)(w1p + 4);
            *(float4*)(w1v + 8)  = *(const float4*)(w1p + 8);
            *(float4*)(w1v + 12) = *(const float4*)(w1p + 12);
            *(float4*)(w2v + 0)  = *(const float4*)(w2p + 0);
            *(float4*)(w2v + 4)  = *(const float4*)(w2p + 4);
            *(float4*)(w2v + 8)  = *(const float4*)(w2p + 8);
            *(float4*)(w2v + 12) = *(const float4*)(w2p + 12);
#pragma unroll
            for (int i = 0; i < 4; ++i) {
                float x1 = (kk == 0) ? a1[i].x : (kk == 1) ? a1[i].y : (kk == 2) ? a1[i].z : a1[i].w;
                float x2 = (kk == 0) ? a2[i].x : (kk == 1) ? a2[i].y : (kk == 2) ? a2[i].z : a2[i].w;
#pragma unroll
                for (int j = 0; j < 16; ++j)
                    acc[i][j] = fmaf(x1, w1v[j], fmaf(x2, w2v[j], acc[i][j]));
            }
        }
    }
    float bv[16];
    *(float4*)(bv + 0)  = *(const float4*)(b1 + c0 + 0);
    *(float4*)(bv + 4)  = *(const float4*)(b1 + c0 + 4);
    *(float4*)(bv + 8)  = *(const float4*)(b1 + c0 + 8);
    *(float4*)(bv + 12) = *(const float4*)(b1 + c0 + 12);
#pragma unroll
    for (int i = 0; i < 4; ++i) {
        int n = n0 + i;
        if (n < NN) {
            float* orow = out + (size_t)n * 128 + c0;
#pragma unroll
            for (int j4 = 0; j4 < 4; ++j4) {
                float4 v;
                v.x = gelu_f(acc[i][j4 * 4 + 0] + bv[j4 * 4 + 0]);
                v.y = gelu_f(acc[i][j4 * 4 + 1] + bv[j4 * 4 + 1]);
                v.z = gelu_f(acc[i][j4 * 4 + 2] + bv[j4 * 4 + 2]);
                v.w = gelu_f(acc[i][j4 * 4 + 3] + bv[j4 * 4 + 3]);
                *(float4*)(orow + j4 * 4) = v;
            }
        }
    }
}

// ---------------- fused gate: gate[n] = gelu(H@Wg1+bg1) . Wg2 + bg2 ----------------
__global__ __launch_bounds__(256) void k_gatef(const float* __restrict__ H, const float* __restrict__ Wg1,
                                               const float* __restrict__ bg1, const float* __restrict__ Wg2,
                                               const float* __restrict__ bg2, float* __restrict__ gate) {
    const int t = threadIdx.x;
    const int cg = t & 7;
    const int ng = t >> 3;
    const int n0 = blockIdx.x * 128 + ng * 4;
    const int c0 = cg * 16;
    float acc[4][16];
#pragma unroll
    for (int i = 0; i < 4; ++i)
#pragma unroll
        for (int j = 0; j < 16; ++j) acc[i][j] = 0.f;
    const float* r1[4];
#pragma unroll
    for (int i = 0; i < 4; ++i) {
        int n = n0 + i;
        if (n >= NN) n = NN - 1;
        r1[i] = H + (size_t)n * 128;
    }
    for (int k = 0; k < 128; k += 4) {
        float4 a1[4];
#pragma unroll
        for (int i = 0; i < 4; ++i) a1[i] = *(const float4*)(r1[i] + k);
#pragma unroll
        for (int kk = 0; kk < 4; ++kk) {
            float w1v[16];
            const float* w1p = Wg1 + (k + kk) * 128 + c0;
            *(float4*)(w1v + 0)  = *(const float4*)(w1p + 0);
            *(float4*)(w1v + 4)  = *(const float4*)(w1p + 4);
            *(float4*)(w1v + 8)  = *(const float4*)(w1p + 8);
            *(float4*)(w1v + 12) = *(const float4*)(w1p + 12);
#pragma unroll
            for (int i = 0; i < 4; ++i) {
                float x1 = (kk == 0) ? a1[i].x : (kk == 1) ? a1[i].y : (kk == 2) ? a1[i].z : a1[i].w;
#pragma unroll
                for (int j = 0; j < 16; ++j)
                    acc[i][j] = fmaf(x1, w1v[j], acc[i][j]);
            }
        }
    }
    float bv[16], gv[16];
    *(float4*)(bv + 0)  = *(const float4*)(bg1 + c0 + 0);
    *(float4*)(bv + 4)  = *(const float4*)(bg1 + c0 + 4);
    *(float4*)(bv + 8)  = *(const float4*)(bg1 + c0 + 8);
    *(float4*)(bv + 12) = *(const float4*)(bg1 + c0 + 12);
    *(float4*)(gv + 0)  = *(const float4*)(Wg2 + c0 + 0);
    *(float4*)(gv + 4)  = *(const float4*)(Wg2 + c0 + 4);
    *(float4*)(gv + 8)  = *(const float4*)(Wg2 + c0 + 8);
    *(float4*)(gv + 12) = *(const float4*)(Wg2 + c0 + 12);
    float bg2v = bg2[0];
    float part[4];
#pragma unroll
    for (int i = 0; i < 4; ++i) {
        float p = 0.f;
#pragma unroll
        for (int j = 0; j < 16; ++j) p += gelu_f(acc[i][j] + bv[j]) * gv[j];
        part[i] = p;
    }
#pragma unroll
    for (int m = 1; m < 8; m <<= 1) {
#pragma unroll
        for (int i = 0; i < 4; ++i) part[i] += __shfl_xor(part[i], m);
    }
    if (cg == 0) {
#pragma unroll
        for (int i = 0; i < 4; ++i) {
            int n = n0 + i;
            if (n < NN) gate[n] = part[i] + bg2v;
        }
    }
}

// ---------------- per-graph attention pool + head ----------------
__global__ __launch_bounds__(256) void k_pool(const float* __restrict__ H, const float* __restrict__ gate,
                                              const int* __restrict__ batch, const float* __restrict__ Wh,
                                              const float* __restrict__ bh, float* __restrict__ out) {
    int g = blockIdx.x;
    int lo = 0, hi = NN;
    while (lo < hi) { int mid = (lo + hi) >> 1; if (batch[mid] < g) lo = mid + 1; else hi = mid; }
    int start = lo;
    lo = start; hi = NN;
    while (lo < hi) { int mid = (lo + hi) >> 1; if (batch[mid] < g + 1) lo = mid + 1; else hi = mid; }
    int endp = lo;

    __shared__ float red[256];
    int tid = threadIdx.x;

    float m = -1e30f;
    for (int i = start + tid; i < endp; i += 256) m = fmaxf(m, gate[i]);
    red[tid] = m;
    __syncthreads();
    for (int off = 128; off; off >>= 1) {
        if (tid < off) red[tid] = fmaxf(red[tid], red[tid + off]);
        __syncthreads();
    }
    m = red[0];
    __syncthreads();

    float s = 0.f;
    for (int i = start + tid; i < endp; i += 256) s += expf(gate[i] - m);
    red[tid] = s;
    __syncthreads();
    for (int off = 128; off; off >>= 1) {
        if (tid < off) red[tid] += red[tid + off];
        __syncthreads();
    }
    float denom = red[0];
    __syncthreads();

    int c = tid & 127, half = tid >> 7;
    float acc = 0.f;
    for (int i = start + half; i < endp; i += 2)
        acc += expf(gate[i] - m) * H[(size_t)i * 128 + c];
    red[tid] = acc;
    __syncthreads();
    if (tid < 128) {
        float gvv = (red[tid] + red[tid + 128]) / denom;
        red[tid] = gvv * Wh[c];
    }
    __syncthreads();
    for (int off = 64; off; off >>= 1) {
        if (tid < off) red[tid] += red[tid + off];
        __syncthreads();
    }
    if (tid == 0) out[g] = red[0] + bh[0];
}

extern "C" void kernel_launch(void* const* d_in, const int* in_sizes, int n_in,
                              void* d_out, int out_size, void* d_ws, size_t ws_size,
                              hipStream_t stream) {
    (void)in_sizes; (void)n_in; (void)out_size; (void)ws_size;
    const float* x   = (const float*)d_in[0];
    const int*  ei   = (const int*)d_in[1];
    const int*  batch= (const int*)d_in[2];
    const float* Wl0 = (const float*)d_in[3];
    const float* bl0 = (const float*)d_in[4];
    const float* Wr0 = (const float*)d_in[5];
    const float* Wl1 = (const float*)d_in[6];
    const float* bl1 = (const float*)d_in[7];
    const float* Wr1 = (const float*)d_in[8];
    const float* Wg1 = (const float*)d_in[9];
    const float* bg1 = (const float*)d_in[10];
    const float* Wg2 = (const float*)d_in[11];
    const float* bg2 = (const float*)d_in[12];
    const float* Wh  = (const float*)d_in[13];
    const float* bh  = (const float*)d_in[14];
    float* out = (float*)d_out;

    const int* srcp = ei;
    const int* dstp = ei + NE;

    char* w = (char*)d_ws;
    size_t off = 0;
    auto alloc = [&](size_t bytes) { void* p = w + off; off += (bytes + 255) & ~(size_t)255; return p; };
    float* bufA  = (float*)alloc((size_t)NN * 128 * 4);  // agg / h2
    float* bufH  = (float*)alloc((size_t)NN * 128 * 4);  // h1
    float* gate  = (float*)alloc((size_t)NN * 4);
    int* cnt     = (int*)alloc((size_t)NN * 4);
    int* rowp    = (int*)alloc((size_t)(NN + 1) * 4);
    int* fill    = (int*)alloc((size_t)NN * 4);
    int* cidx    = (int*)alloc((size_t)NE * 4);
    int* blksum  = (int*)alloc(128 * 4);
    int* blkoff  = (int*)alloc(128 * 4);

    hipMemsetAsync(cnt, 0, (size_t)NN * 4, stream);
    hipMemsetAsync(fill, 0, (size_t)NN * 4, stream);

    // CSR build (reused by both layers)
    k_hist<<<(NE + 255) / 256, 256, 0, stream>>>(dstp, cnt);
    int nb = (NN + SB - 1) / SB;
    k_scan1<<<nb, SB, 0, stream>>>(cnt, rowp, blksum);
    k_scan2<<<1, 128, 0, stream>>>(blksum, blkoff, nb);
    k_scan3<<<(NN + 1 + 255) / 256, 256, 0, stream>>>(rowp, blkoff);
    k_scatter<<<(NE + 255) / 256, 256, 0, stream>>>(srcp, dstp, rowp, fill, cidx);

    int gb = (NN + 127) / 128;
    // layer 0
    k_agg<<<(NN + 3) / 4, 256, 0, stream>>>(x, rowp, cidx, bufA);
    k_sage<<<gb, 256, 0, stream>>>(bufA, Wl0, bl0, x, Wr0, bufH);      // h1
    // layer 1
    k_agg<<<(NN + 3) / 4, 256, 0, stream>>>(bufH, rowp, cidx, bufA);
    k_sage<<<gb, 256, 0, stream>>>(bufA, Wl1, bl1, bufH, Wr1, bufA);   // h2 (in-place, wave-exclusive rows)
    // gate + pool + head
    k_gatef<<<gb, 256, 0, stream>>>(bufA, Wg1, bg1, Wg2, bg2, gate);
    k_pool<<<NG, 256, 0, stream>>>(bufA, gate, batch, Wh, bh, out);
}

// Round 2
// 933.412 us; speedup vs baseline: 1.5551x; 1.5551x over previous
//
#include <hip/hip_runtime.h>
#include <math.h>

#define NN 100000
#define NE 1600000
#define NG 64

__device__ __forceinline__ float gelu_f(float x) {
    return 0.5f * x * (1.0f + erff(x * 0.7071067811865475f));
}

// ---------------- CSR build ----------------
__global__ void k_hist(const int* __restrict__ dstp, int* __restrict__ cnt) {
    int e = blockIdx.x * 256 + threadIdx.x;
    if (e < NE) atomicAdd(&cnt[dstp[e]], 1);
}

#define SB 1024
__global__ __launch_bounds__(SB) void k_scan1(const int* __restrict__ cnt, int* __restrict__ rowp,
                                              int* __restrict__ blksum) {
    __shared__ int s[SB];
    int tid = threadIdx.x;
    int i = blockIdx.x * SB + tid;
    int v = (i < NN) ? cnt[i] : 0;
    int run = v;
    s[tid] = v;
    __syncthreads();
    for (int off = 1; off < SB; off <<= 1) {
        int t = (tid >= off) ? s[tid - off] : 0;
        __syncthreads();
        run += t;
        s[tid] = run;
        __syncthreads();
    }
    if (i < NN) rowp[i] = run - v;            // exclusive within block
    if (tid == SB - 1) blksum[blockIdx.x] = run;
}

__global__ void k_scan2(const int* __restrict__ blksum, int* __restrict__ blkoff, int nb) {
    __shared__ int s[128];
    int tid = threadIdx.x;
    int v = (tid < nb) ? blksum[tid] : 0;
    int run = v;
    s[tid] = v;
    __syncthreads();
    for (int off = 1; off < 128; off <<= 1) {
        int t = (tid >= off) ? s[tid - off] : 0;
        __syncthreads();
        run += t;
        s[tid] = run;
        __syncthreads();
    }
    if (tid < nb) blkoff[tid] = run - v;
}

__global__ void k_scan3(int* __restrict__ rowp, const int* __restrict__ blkoff) {
    int i = blockIdx.x * 256 + threadIdx.x;
    if (i < NN) rowp[i] += blkoff[i >> 10];
    else if (i == NN) rowp[NN] = NE;
}

__global__ void k_scatter(const int* __restrict__ srcp, const int* __restrict__ dstp,
                          const int* __restrict__ rowp, int* __restrict__ fill,
                          int* __restrict__ cidx) {
    int e = blockIdx.x * 256 + threadIdx.x;
    if (e < NE) {
        int d = dstp[e];
        int pos = atomicAdd(&fill[d], 1);
        cidx[rowp[d] + pos] = srcp[e];
    }
}

// ---------------- mean-aggregate: one wave per node, 4 edges in flight ----------------
__global__ __launch_bounds__(256) void k_agg(const float* __restrict__ xin, const int* __restrict__ rowp,
                                             const int* __restrict__ cidx, float* __restrict__ agg) {
    int node = (blockIdx.x * 256 + threadIdx.x) >> 6;
    int lane = threadIdx.x & 63;
    if (node >= NN) return;
    int beg = rowp[node], endp = rowp[node + 1];
    const float2* x2 = (const float2*)xin;
    float ax = 0.f, ay = 0.f;
    int e = beg;
    for (; e + 3 < endp; e += 4) {
        int s0 = cidx[e], s1 = cidx[e + 1], s2 = cidx[e + 2], s3 = cidx[e + 3];
        float2 v0 = x2[(size_t)s0 * 64 + lane];
        float2 v1 = x2[(size_t)s1 * 64 + lane];
        float2 v2 = x2[(size_t)s2 * 64 + lane];
        float2 v3 = x2[(size_t)s3 * 64 + lane];
        ax += (v0.x + v1.x) + (v2.x + v3.x);
        ay += (v0.y + v1.y) + (v2.y + v3.y);
    }
    for (; e < endp; ++e) {
        int s0 = cidx[e];
        float2 v0 = x2[(size_t)s0 * 64 + lane];
        ax += v0.x;
        ay += v0.y;
    }
    float inv = 1.0f / fmaxf((float)(endp - beg), 1.0f);
    float2 r;
    r.x = ax * inv;
    r.y = ay * inv;
    ((float2*)agg)[(size_t)node * 64 + lane] = r;
}

// ---------------- fused SAGE layer: out = gelu(A1@W1 + b1 + A2@W2) ----------------
// 512 threads; tile = 256 nodes x 128 cols; thread = 8 nodes x 8 cols.
// W1,W2 staged in 64KB LDS in two 64-row k-halves; W reads are 16-lane-broadcast
// ds_read_b128 (2-way bank alias = free).
// In-place safety (out may alias A1): each node row is read/written ONLY by the 16
// consecutive threads (cg 0..15, same wave) owning it — wave lockstep orders all
// k-loop loads before epilogue stores. Clamped tail reads may race but their
// results are discarded (store guarded by n < NN).
__global__ __launch_bounds__(512, 2) void k_sage(const float* A1, const float* __restrict__ W1,
                                                 const float* __restrict__ b1, const float* A2,
                                                 const float* __restrict__ W2, float* out) {
    __shared__ float ws[16384];  // [0..8191]: W1 k-half [64][128]; [8192..]: W2 k-half
    const int t = threadIdx.x;
    const int cg = t & 15;
    const int ng = t >> 4;
    const int n0 = blockIdx.x * 256 + ng * 8;
    const int c0 = cg * 8;
    float acc[8][8];
#pragma unroll
    for (int i = 0; i < 8; ++i)
#pragma unroll
        for (int j = 0; j < 8; ++j) acc[i][j] = 0.f;
    const float *r1[8], *r2[8];
#pragma unroll
    for (int i = 0; i < 8; ++i) {
        int n = n0 + i;
        if (n >= NN) n = NN - 1;  // clamp loads; stores guarded below
        r1[i] = A1 + (size_t)n * 128;
        r2[i] = A2 + (size_t)n * 128;
    }
    for (int kb = 0; kb < 128; kb += 64) {
        __syncthreads();  // previous half fully consumed before overwrite
        for (int idx = t; idx < 2048; idx += 512) {  // 64 rows x 32 float4-chunks
            ((float4*)ws)[idx]        = ((const float4*)(W1 + kb * 128))[idx];
            ((float4*)ws)[2048 + idx] = ((const float4*)(W2 + kb * 128))[idx];
        }
        __syncthreads();
        for (int k2 = 0; k2 < 64; k2 += 4) {
            const int k = kb + k2;
            float w1v[4][8], w2v[4][8];
#pragma unroll
            for (int kk = 0; kk < 4; ++kk) {
                *(float4*)&w1v[kk][0] = *(const float4*)&ws[(k2 + kk) * 128 + c0];
                *(float4*)&w1v[kk][4] = *(const float4*)&ws[(k2 + kk) * 128 + c0 + 4];
                *(float4*)&w2v[kk][0] = *(const float4*)&ws[8192 + (k2 + kk) * 128 + c0];
                *(float4*)&w2v[kk][4] = *(const float4*)&ws[8192 + (k2 + kk) * 128 + c0 + 4];
            }
#pragma unroll
            for (int h = 0; h < 2; ++h) {
                float4 a1[4], a2[4];
#pragma unroll
                for (int i = 0; i < 4; ++i) {
                    a1[i] = *(const float4*)(r1[h * 4 + i] + k);
                    a2[i] = *(const float4*)(r2[h * 4 + i] + k);
                }
#pragma unroll
                for (int i = 0; i < 4; ++i) {
#pragma unroll
                    for (int kk = 0; kk < 4; ++kk) {
                        float x1 = (kk == 0) ? a1[i].x : (kk == 1) ? a1[i].y : (kk == 2) ? a1[i].z : a1[i].w;
                        float x2 = (kk == 0) ? a2[i].x : (kk == 1) ? a2[i].y : (kk == 2) ? a2[i].z : a2[i].w;
#pragma unroll
                        for (int j = 0; j < 8; ++j)
                            acc[h * 4 + i][j] = fmaf(x1, w1v[kk][j], fmaf(x2, w2v[kk][j], acc[h * 4 + i][j]));
                    }
                }
            }
        }
    }
    float bv[8];
    *(float4*)&bv[0] = *(const float4*)(b1 + c0);
    *(float4*)&bv[4] = *(const float4*)(b1 + c0 + 4);
#pragma unroll
    for (int i = 0; i < 8; ++i) {
        int n = n0 + i;
        if (n < NN) {
            float* orow = out + (size_t)n * 128 + c0;
            float4 v;
            v.x = gelu_f(acc[i][0] + bv[0]);
            v.y = gelu_f(acc[i][1] + bv[1]);
            v.z = gelu_f(acc[i][2] + bv[2]);
            v.w = gelu_f(acc[i][3] + bv[3]);
            *(float4*)orow = v;
            v.x = gelu_f(acc[i][4] + bv[4]);
            v.y = gelu_f(acc[i][5] + bv[5]);
            v.z = gelu_f(acc[i][6] + bv[6]);
            v.w = gelu_f(acc[i][7] + bv[7]);
            *(float4*)(orow + 4) = v;
        }
    }
}

// ---------------- fused gate: gate[n] = gelu(H@Wg1+bg1) . Wg2   (bg2 dropped:
// per-graph softmax is invariant to a constant shift of the scores) ----------------
__global__ __launch_bounds__(512, 2) void k_gatef(const float* __restrict__ H, const float* __restrict__ Wg1,
                                                  const float* __restrict__ bg1, const float* __restrict__ Wg2,
                                                  float* __restrict__ gate) {
    __shared__ float wgs[16384];  // full Wg1 [128][128]
    const int t = threadIdx.x;
    for (int idx = t; idx < 4096; idx += 512)
        ((float4*)wgs)[idx] = ((const float4*)Wg1)[idx];
    __syncthreads();
    const int cg = t & 15;
    const int ng = t >> 4;
    const int n0 = blockIdx.x * 256 + ng * 8;
    const int c0 = cg * 8;
    float acc[8][8];
#pragma unroll
    for (int i = 0; i < 8; ++i)
#pragma unroll
        for (int j = 0; j < 8; ++j) acc[i][j] = 0.f;
    const float* r1[8];
#pragma unroll
    for (int i = 0; i < 8; ++i) {
        int n = n0 + i;
        if (n >= NN) n = NN - 1;
        r1[i] = H + (size_t)n * 128;
    }
    for (int k = 0; k < 128; k += 4) {
        float w1v[4][8];
#pragma unroll
        for (int kk = 0; kk < 4; ++kk) {
            *(float4*)&w1v[kk][0] = *(const float4*)&wgs[(k + kk) * 128 + c0];
            *(float4*)&w1v[kk][4] = *(const float4*)&wgs[(k + kk) * 128 + c0 + 4];
        }
#pragma unroll
        for (int h = 0; h < 2; ++h) {
            float4 a1[4];
#pragma unroll
            for (int i = 0; i < 4; ++i) a1[i] = *(const float4*)(r1[h * 4 + i] + k);
#pragma unroll
            for (int i = 0; i < 4; ++i) {
#pragma unroll
                for (int kk = 0; kk < 4; ++kk) {
                    float x1 = (kk == 0) ? a1[i].x : (kk == 1) ? a1[i].y : (kk == 2) ? a1[i].z : a1[i].w;
#pragma unroll
                    for (int j = 0; j < 8; ++j)
                        acc[h * 4 + i][j] = fmaf(x1, w1v[kk][j], acc[h * 4 + i][j]);
                }
            }
        }
    }
    float bv[8], gv[8];
    *(float4*)&bv[0] = *(const float4*)(bg1 + c0);
    *(float4*)&bv[4] = *(const float4*)(bg1 + c0 + 4);
    *(float4*)&gv[0] = *(const float4*)(Wg2 + c0);
    *(float4*)&gv[4] = *(const float4*)(Wg2 + c0 + 4);
    float part[8];
#pragma unroll
    for (int i = 0; i < 8; ++i) {
        float p = 0.f;
#pragma unroll
        for (int j = 0; j < 8; ++j) p += gelu_f(acc[i][j] + bv[j]) * gv[j];
        part[i] = p;
    }
#pragma unroll
    for (int m = 1; m < 16; m <<= 1) {
#pragma unroll
        for (int i = 0; i < 8; ++i) part[i] += __shfl_xor(part[i], m);
    }
    if (cg == 0) {
#pragma unroll
        for (int i = 0; i < 8; ++i) {
            int n = n0 + i;
            if (n < NN) gate[n] = part[i];
        }
    }
}

// ---------------- per-graph attention pool + head ----------------
__global__ __launch_bounds__(256) void k_pool(const float* __restrict__ H, const float* __restrict__ gate,
                                              const int* __restrict__ batch, const float* __restrict__ Wh,
                                              const float* __restrict__ bh, float* __restrict__ out) {
    int g = blockIdx.x;
    int lo = 0, hi = NN;
    while (lo < hi) { int mid = (lo + hi) >> 1; if (batch[mid] < g) lo = mid + 1; else hi = mid; }
    int start = lo;
    lo = start; hi = NN;
    while (lo < hi) { int mid = (lo + hi) >> 1; if (batch[mid] < g + 1) lo = mid + 1; else hi = mid; }
    int endp = lo;

    __shared__ float red[256];
    int tid = threadIdx.x;

    float m = -1e30f;
    for (int i = start + tid; i < endp; i += 256) m = fmaxf(m, gate[i]);
    red[tid] = m;
    __syncthreads();
    for (int off = 128; off; off >>= 1) {
        if (tid < off) red[tid] = fmaxf(red[tid], red[tid + off]);
        __syncthreads();
    }
    m = red[0];
    __syncthreads();

    float s = 0.f;
    for (int i = start + tid; i < endp; i += 256) s += expf(gate[i] - m);
    red[tid] = s;
    __syncthreads();
    for (int off = 128; off; off >>= 1) {
        if (tid < off) red[tid] += red[tid + off];
        __syncthreads();
    }
    float denom = red[0];
    __syncthreads();

    int c = tid & 127, half = tid >> 7;
    float acc = 0.f;
    for (int i = start + half; i < endp; i += 2)
        acc += expf(gate[i] - m) * H[(size_t)i * 128 + c];
    red[tid] = acc;
    __syncthreads();
    if (tid < 128) {
        float gvv = (red[tid] + red[tid + 128]) / denom;
        red[tid] = gvv * Wh[c];
    }
    __syncthreads();
    for (int off = 64; off; off >>= 1) {
        if (tid < off) red[tid] += red[tid + off];
        __syncthreads();
    }
    if (tid == 0) out[g] = red[0] + bh[0];
}

extern "C" void kernel_launch(void* const* d_in, const int* in_sizes, int n_in,
                              void* d_out, int out_size, void* d_ws, size_t ws_size,
                              hipStream_t stream) {
    (void)in_sizes; (void)n_in; (void)out_size; (void)ws_size;
    const float* x   = (const float*)d_in[0];
    const int*  ei   = (const int*)d_in[1];
    const int*  batch= (const int*)d_in[2];
    const float* Wl0 = (const float*)d_in[3];
    const float* bl0 = (const float*)d_in[4];
    const float* Wr0 = (const float*)d_in[5];
    const float* Wl1 = (const float*)d_in[6];
    const float* bl1 = (const float*)d_in[7];
    const float* Wr1 = (const float*)d_in[8];
    const float* Wg1 = (const float*)d_in[9];
    const float* bg1 = (const float*)d_in[10];
    const float* Wg2 = (const float*)d_in[11];
    const float* Wh  = (const float*)d_in[13];
    const float* bh  = (const float*)d_in[14];
    float* out = (float*)d_out;

    const int* srcp = ei;
    const int* dstp = ei + NE;

    char* w = (char*)d_ws;
    size_t off = 0;
    auto alloc = [&](size_t bytes) { void* p = w + off; off += (bytes + 255) & ~(size_t)255; return p; };
    float* bufA  = (float*)alloc((size_t)NN * 128 * 4);  // agg / h2
    float* bufH  = (float*)alloc((size_t)NN * 128 * 4);  // h1
    float* gate  = (float*)alloc((size_t)NN * 4);
    int* cnt     = (int*)alloc((size_t)NN * 4);
    int* rowp    = (int*)alloc((size_t)(NN + 1) * 4);
    int* fill    = (int*)alloc((size_t)NN * 4);
    int* cidx    = (int*)alloc((size_t)NE * 4);
    int* blksum  = (int*)alloc(128 * 4);
    int* blkoff  = (int*)alloc(128 * 4);

    hipMemsetAsync(cnt, 0, (size_t)NN * 4, stream);
    hipMemsetAsync(fill, 0, (size_t)NN * 4, stream);

    // CSR build (reused by both layers)
    k_hist<<<(NE + 255) / 256, 256, 0, stream>>>(dstp, cnt);
    int nb = (NN + SB - 1) / SB;
    k_scan1<<<nb, SB, 0, stream>>>(cnt, rowp, blksum);
    k_scan2<<<1, 128, 0, stream>>>(blksum, blkoff, nb);
    k_scan3<<<(NN + 1 + 255) / 256, 256, 0, stream>>>(rowp, blkoff);
    k_scatter<<<(NE + 255) / 256, 256, 0, stream>>>(srcp, dstp, rowp, fill, cidx);

    int gs = (NN + 255) / 256;  // 391 blocks of 512 threads (256-node tiles)
    // layer 0
    k_agg<<<(NN + 3) / 4, 256, 0, stream>>>(x, rowp, cidx, bufA);
    k_sage<<<gs, 512, 0, stream>>>(bufA, Wl0, bl0, x, Wr0, bufH);      // h1
    // layer 1
    k_agg<<<(NN + 3) / 4, 256, 0, stream>>>(bufH, rowp, cidx, bufA);
    k_sage<<<gs, 512, 0, stream>>>(bufA, Wl1, bl1, bufH, Wr1, bufA);   // h2 in-place (wave-owned rows)
    // gate + pool + head
    k_gatef<<<gs, 512, 0, stream>>>(bufA, Wg1, bg1, Wg2, gate);
    k_pool<<<NG, 256, 0, stream>>>(bufA, gate, batch, Wh, bh, out);
}

// Round 3
// 784.961 us; speedup vs baseline: 1.8492x; 1.1891x over previous
//
#include <hip/hip_runtime.h>
#include <math.h>

#define NN 100000
#define NE 1600000
#define NG 64

__device__ __forceinline__ float gelu_f(float x) {
    return 0.5f * x * (1.0f + erff(x * 0.7071067811865475f));
}

// ---------------- CSR build ----------------
__global__ void k_hist(const int* __restrict__ dstp, int* __restrict__ cnt) {
    int e = blockIdx.x * 256 + threadIdx.x;
    if (e < NE) atomicAdd(&cnt[dstp[e]], 1);
}

#define SB 1024
__global__ __launch_bounds__(SB) void k_scan1(const int* __restrict__ cnt, int* __restrict__ rowp,
                                              int* __restrict__ blksum) {
    __shared__ int s[SB];
    int tid = threadIdx.x;
    int i = blockIdx.x * SB + tid;
    int v = (i < NN) ? cnt[i] : 0;
    int run = v;
    s[tid] = v;
    __syncthreads();
    for (int off = 1; off < SB; off <<= 1) {
        int t = (tid >= off) ? s[tid - off] : 0;
        __syncthreads();
        run += t;
        s[tid] = run;
        __syncthreads();
    }
    if (i < NN) rowp[i] = run - v;            // exclusive within block
    if (tid == SB - 1) blksum[blockIdx.x] = run;
}

__global__ void k_scan2(const int* __restrict__ blksum, int* __restrict__ blkoff, int nb) {
    __shared__ int s[128];
    int tid = threadIdx.x;
    int v = (tid < nb) ? blksum[tid] : 0;
    int run = v;
    s[tid] = v;
    __syncthreads();
    for (int off = 1; off < 128; off <<= 1) {
        int t = (tid >= off) ? s[tid - off] : 0;
        __syncthreads();
        run += t;
        s[tid] = run;
        __syncthreads();
    }
    if (tid < nb) blkoff[tid] = run - v;
}

__global__ void k_scan3(int* __restrict__ rowp, const int* __restrict__ blkoff) {
    int i = blockIdx.x * 256 + threadIdx.x;
    if (i < NN) rowp[i] += blkoff[i >> 10];
    else if (i == NN) rowp[NN] = NE;
}

__global__ void k_scatter(const int* __restrict__ srcp, const int* __restrict__ dstp,
                          const int* __restrict__ rowp, int* __restrict__ fill,
                          int* __restrict__ cidx) {
    int e = blockIdx.x * 256 + threadIdx.x;
    if (e < NE) {
        int d = dstp[e];
        int pos = atomicAdd(&fill[d], 1);
        cidx[rowp[d] + pos] = srcp[e];
    }
}

// ---------------- mean-aggregate: 32 lanes x float4 per node, 2 nodes/wave ----------------
__global__ __launch_bounds__(256) void k_agg(const float* __restrict__ xin, const int* __restrict__ rowp,
                                             const int* __restrict__ cidx, float* __restrict__ agg) {
    int tid = blockIdx.x * 256 + threadIdx.x;
    int node = tid >> 5;
    int lane = tid & 31;
    if (node >= NN) return;
    int beg = rowp[node], endp = rowp[node + 1];
    const float4* x4 = (const float4*)xin;
    float sx = 0.f, sy = 0.f, sz = 0.f, sw = 0.f;
    int e = beg;
    for (; e + 3 < endp; e += 4) {
        int i0 = cidx[e], i1 = cidx[e + 1], i2 = cidx[e + 2], i3 = cidx[e + 3];
        float4 v0 = x4[(size_t)i0 * 32 + lane];
        float4 v1 = x4[(size_t)i1 * 32 + lane];
        float4 v2 = x4[(size_t)i2 * 32 + lane];
        float4 v3 = x4[(size_t)i3 * 32 + lane];
        sx += (v0.x + v1.x) + (v2.x + v3.x);
        sy += (v0.y + v1.y) + (v2.y + v3.y);
        sz += (v0.z + v1.z) + (v2.z + v3.z);
        sw += (v0.w + v1.w) + (v2.w + v3.w);
    }
    for (; e < endp; ++e) {
        int i0 = cidx[e];
        float4 v0 = x4[(size_t)i0 * 32 + lane];
        sx += v0.x; sy += v0.y; sz += v0.z; sw += v0.w;
    }
    float inv = 1.0f / fmaxf((float)(endp - beg), 1.0f);
    float4 r;
    r.x = sx * inv; r.y = sy * inv; r.z = sz * inv; r.w = sw * inv;
    ((float4*)agg)[(size_t)node * 32 + lane] = r;
}

// ---------------- fused SAGE layer: out = gelu(A1@W1 + b1 + A2@W2) ----------------
// 512 threads; tile = 256 nodes x 128 cols; thread = 8 nodes x 8 cols.
// W1,W2 staged in 64KB LDS in two 64-row k-halves.
// In-place safety (out may alias A1): each node row is read/written ONLY by the 16
// consecutive threads (same wave) owning it; wave lockstep orders k-loop loads
// before epilogue stores. Clamped tail reads are discarded.
__global__ __launch_bounds__(512, 2) void k_sage(const float* A1, const float* __restrict__ W1,
                                                 const float* __restrict__ b1, const float* A2,
                                                 const float* __restrict__ W2, float* out) {
    __shared__ float ws[16384];  // [0..8191]: W1 k-half [64][128]; [8192..]: W2 k-half
    const int t = threadIdx.x;
    const int cg = t & 15;
    const int ng = t >> 4;
    const int n0 = blockIdx.x * 256 + ng * 8;
    const int c0 = cg * 8;
    float acc[8][8];
#pragma unroll
    for (int i = 0; i < 8; ++i)
#pragma unroll
        for (int j = 0; j < 8; ++j) acc[i][j] = 0.f;
    const float *r1[8], *r2[8];
#pragma unroll
    for (int i = 0; i < 8; ++i) {
        int n = n0 + i;
        if (n >= NN) n = NN - 1;  // clamp loads; stores guarded below
        r1[i] = A1 + (size_t)n * 128;
        r2[i] = A2 + (size_t)n * 128;
    }
    for (int kb = 0; kb < 128; kb += 64) {
        __syncthreads();  // previous half fully consumed before overwrite
        for (int idx = t; idx < 2048; idx += 512) {  // 64 rows x 32 float4-chunks
            ((float4*)ws)[idx]        = ((const float4*)(W1 + kb * 128))[idx];
            ((float4*)ws)[2048 + idx] = ((const float4*)(W2 + kb * 128))[idx];
        }
        __syncthreads();
        for (int k2 = 0; k2 < 64; k2 += 4) {
            const int k = kb + k2;
            float w1v[4][8], w2v[4][8];
#pragma unroll
            for (int kk = 0; kk < 4; ++kk) {
                *(float4*)&w1v[kk][0] = *(const float4*)&ws[(k2 + kk) * 128 + c0];
                *(float4*)&w1v[kk][4] = *(const float4*)&ws[(k2 + kk) * 128 + c0 + 4];
                *(float4*)&w2v[kk][0] = *(const float4*)&ws[8192 + (k2 + kk) * 128 + c0];
                *(float4*)&w2v[kk][4] = *(const float4*)&ws[8192 + (k2 + kk) * 128 + c0 + 4];
            }
#pragma unroll
            for (int h = 0; h < 2; ++h) {
                float4 a1[4], a2[4];
#pragma unroll
                for (int i = 0; i < 4; ++i) {
                    a1[i] = *(const float4*)(r1[h * 4 + i] + k);
                    a2[i] = *(const float4*)(r2[h * 4 + i] + k);
                }
#pragma unroll
                for (int i = 0; i < 4; ++i) {
#pragma unroll
                    for (int kk = 0; kk < 4; ++kk) {
                        float x1 = (kk == 0) ? a1[i].x : (kk == 1) ? a1[i].y : (kk == 2) ? a1[i].z : a1[i].w;
                        float x2 = (kk == 0) ? a2[i].x : (kk == 1) ? a2[i].y : (kk == 2) ? a2[i].z : a2[i].w;
#pragma unroll
                        for (int j = 0; j < 8; ++j)
                            acc[h * 4 + i][j] = fmaf(x1, w1v[kk][j], fmaf(x2, w2v[kk][j], acc[h * 4 + i][j]));
                    }
                }
            }
        }
    }
    float bv[8];
    *(float4*)&bv[0] = *(const float4*)(b1 + c0);
    *(float4*)&bv[4] = *(const float4*)(b1 + c0 + 4);
#pragma unroll
    for (int i = 0; i < 8; ++i) {
        int n = n0 + i;
        if (n < NN) {
            float* orow = out + (size_t)n * 128 + c0;
            float4 v;
            v.x = gelu_f(acc[i][0] + bv[0]);
            v.y = gelu_f(acc[i][1] + bv[1]);
            v.z = gelu_f(acc[i][2] + bv[2]);
            v.w = gelu_f(acc[i][3] + bv[3]);
            *(float4*)orow = v;
            v.x = gelu_f(acc[i][4] + bv[4]);
            v.y = gelu_f(acc[i][5] + bv[5]);
            v.z = gelu_f(acc[i][6] + bv[6]);
            v.w = gelu_f(acc[i][7] + bv[7]);
            *(float4*)(orow + 4) = v;
        }
    }
}

// ---------------- fused gate: gate[n] = gelu(H@Wg1+bg1) . Wg2   (bg2 dropped:
// per-graph softmax is invariant to a constant shift of the scores) ----------------
__global__ __launch_bounds__(512, 2) void k_gatef(const float* __restrict__ H, const float* __restrict__ Wg1,
                                                  const float* __restrict__ bg1, const float* __restrict__ Wg2,
                                                  float* __restrict__ gate) {
    __shared__ float wgs[16384];  // full Wg1 [128][128]
    const int t = threadIdx.x;
    for (int idx = t; idx < 4096; idx += 512)
        ((float4*)wgs)[idx] = ((const float4*)Wg1)[idx];
    __syncthreads();
    const int cg = t & 15;
    const int ng = t >> 4;
    const int n0 = blockIdx.x * 256 + ng * 8;
    const int c0 = cg * 8;
    float acc[8][8];
#pragma unroll
    for (int i = 0; i < 8; ++i)
#pragma unroll
        for (int j = 0; j < 8; ++j) acc[i][j] = 0.f;
    const float* r1[8];
#pragma unroll
    for (int i = 0; i < 8; ++i) {
        int n = n0 + i;
        if (n >= NN) n = NN - 1;
        r1[i] = H + (size_t)n * 128;
    }
    for (int k = 0; k < 128; k += 4) {
        float w1v[4][8];
#pragma unroll
        for (int kk = 0; kk < 4; ++kk) {
            *(float4*)&w1v[kk][0] = *(const float4*)&wgs[(k + kk) * 128 + c0];
            *(float4*)&w1v[kk][4] = *(const float4*)&wgs[(k + kk) * 128 + c0 + 4];
        }
#pragma unroll
        for (int h = 0; h < 2; ++h) {
            float4 a1[4];
#pragma unroll
            for (int i = 0; i < 4; ++i) a1[i] = *(const float4*)(r1[h * 4 + i] + k);
#pragma unroll
            for (int i = 0; i < 4; ++i) {
#pragma unroll
                for (int kk = 0; kk < 4; ++kk) {
                    float x1 = (kk == 0) ? a1[i].x : (kk == 1) ? a1[i].y : (kk == 2) ? a1[i].z : a1[i].w;
#pragma unroll
                    for (int j = 0; j < 8; ++j)
                        acc[h * 4 + i][j] = fmaf(x1, w1v[kk][j], acc[h * 4 + i][j]);
                }
            }
        }
    }
    float bv[8], gv[8];
    *(float4*)&bv[0] = *(const float4*)(bg1 + c0);
    *(float4*)&bv[4] = *(const float4*)(bg1 + c0 + 4);
    *(float4*)&gv[0] = *(const float4*)(Wg2 + c0);
    *(float4*)&gv[4] = *(const float4*)(Wg2 + c0 + 4);
    float part[8];
#pragma unroll
    for (int i = 0; i < 8; ++i) {
        float p = 0.f;
#pragma unroll
        for (int j = 0; j < 8; ++j) p += gelu_f(acc[i][j] + bv[j]) * gv[j];
        part[i] = p;
    }
#pragma unroll
    for (int m = 1; m < 16; m <<= 1) {
#pragma unroll
        for (int i = 0; i < 8; ++i) part[i] += __shfl_xor(part[i], m);
    }
    if (cg == 0) {
#pragma unroll
        for (int i = 0; i < 8; ++i) {
            int n = n0 + i;
            if (n < NN) gate[n] = part[i];
        }
    }
}

// ---------------- pooling stage 1: per-graph max + exp-sum over gate ----------------
__global__ __launch_bounds__(256) void k_pstats(const float* __restrict__ gate, const int* __restrict__ batch,
                                                float* __restrict__ gm, float* __restrict__ gden) {
    int g = blockIdx.x;
    int lo = 0, hi = NN;
    while (lo < hi) { int mid = (lo + hi) >> 1; if (batch[mid] < g) lo = mid + 1; else hi = mid; }
    int start = lo;
    lo = start; hi = NN;
    while (lo < hi) { int mid = (lo + hi) >> 1; if (batch[mid] < g + 1) lo = mid + 1; else hi = mid; }
    int endp = lo;

    __shared__ float red[256];
    int tid = threadIdx.x;

    float m = -1e30f;
    for (int i = start + tid; i < endp; i += 256) m = fmaxf(m, gate[i]);
    red[tid] = m;
    __syncthreads();
    for (int off = 128; off; off >>= 1) {
        if (tid < off) red[tid] = fmaxf(red[tid], red[tid + off]);
        __syncthreads();
    }
    m = red[0];
    __syncthreads();

    float s = 0.f;
    for (int i = start + tid; i < endp; i += 256) s += expf(gate[i] - m);
    red[tid] = s;
    __syncthreads();
    for (int off = 128; off; off >>= 1) {
        if (tid < off) red[tid] += red[tid + off];
        __syncthreads();
    }
    if (tid == 0) { gm[g] = m; gden[g] = red[0]; }
}

// ---------------- pooling stage 2: node-parallel weighted accumulate ----------------
// 128-node tile per block; 2 threads per column. Sorted batch -> register-run
// accumulation, one atomicAdd per (graph-run, thread).
__global__ __launch_bounds__(256) void k_pacc(const float* __restrict__ H, const float* __restrict__ gate,
                                              const int* __restrict__ batch, const float* __restrict__ gm,
                                              const float* __restrict__ gden, float* __restrict__ gacc) {
    int c = threadIdx.x & 127;
    int h = threadIdx.x >> 7;
    int n0 = blockIdx.x * 128;
    int nend = n0 + 128;
    if (nend > NN) nend = NN;
    int i = n0 + h;
    if (i >= nend) return;
    int cur = batch[i];
    float m = gm[cur], invd = 1.0f / gden[cur];
    float acc = 0.f;
    for (; i < nend; i += 2) {
        int gi = batch[i];
        if (gi != cur) {
            atomicAdd(&gacc[cur * 128 + c], acc * invd);
            acc = 0.f;
            cur = gi;
            m = gm[cur];
            invd = 1.0f / gden[cur];
        }
        acc = fmaf(expf(gate[i] - m), H[(size_t)i * 128 + c], acc);
    }
    atomicAdd(&gacc[cur * 128 + c], acc * invd);
}

// ---------------- head: out[g] = g . Wh + bh ----------------
__global__ __launch_bounds__(64) void k_head(const float* __restrict__ gacc, const float* __restrict__ Wh,
                                             const float* __restrict__ bh, float* __restrict__ out) {
    int g = blockIdx.x;
    int l = threadIdx.x;
    float v = gacc[g * 128 + l] * Wh[l] + gacc[g * 128 + 64 + l] * Wh[64 + l];
#pragma unroll
    for (int m = 1; m < 64; m <<= 1) v += __shfl_xor(v, m);
    if (l == 0) out[g] = v + bh[0];
}

extern "C" void kernel_launch(void* const* d_in, const int* in_sizes, int n_in,
                              void* d_out, int out_size, void* d_ws, size_t ws_size,
                              hipStream_t stream) {
    (void)in_sizes; (void)n_in; (void)out_size; (void)ws_size;
    const float* x   = (const float*)d_in[0];
    const int*  ei   = (const int*)d_in[1];
    const int*  batch= (const int*)d_in[2];
    const float* Wl0 = (const float*)d_in[3];
    const float* bl0 = (const float*)d_in[4];
    const float* Wr0 = (const float*)d_in[5];
    const float* Wl1 = (const float*)d_in[6];
    const float* bl1 = (const float*)d_in[7];
    const float* Wr1 = (const float*)d_in[8];
    const float* Wg1 = (const float*)d_in[9];
    const float* bg1 = (const float*)d_in[10];
    const float* Wg2 = (const float*)d_in[11];
    const float* Wh  = (const float*)d_in[13];
    const float* bh  = (const float*)d_in[14];
    float* out = (float*)d_out;

    const int* srcp = ei;
    const int* dstp = ei + NE;

    char* w = (char*)d_ws;
    size_t off = 0;
    auto alloc = [&](size_t bytes) { void* p = w + off; off += (bytes + 255) & ~(size_t)255; return p; };
    float* bufA  = (float*)alloc((size_t)NN * 128 * 4);  // agg / h2
    float* bufH  = (float*)alloc((size_t)NN * 128 * 4);  // h1
    float* gate  = (float*)alloc((size_t)NN * 4);
    int* cnt     = (int*)alloc((size_t)NN * 4);
    int* rowp    = (int*)alloc((size_t)(NN + 1) * 4);
    int* fill    = (int*)alloc((size_t)NN * 4);
    int* cidx    = (int*)alloc((size_t)NE * 4);
    int* blksum  = (int*)alloc(128 * 4);
    int* blkoff  = (int*)alloc(128 * 4);
    float* gm    = (float*)alloc(NG * 4);
    float* gden  = (float*)alloc(NG * 4);
    float* gacc  = (float*)alloc((size_t)NG * 128 * 4);

    hipMemsetAsync(cnt, 0, (size_t)NN * 4, stream);
    hipMemsetAsync(fill, 0, (size_t)NN * 4, stream);
    hipMemsetAsync(gacc, 0, (size_t)NG * 128 * 4, stream);

    // CSR build (reused by both layers)
    k_hist<<<(NE + 255) / 256, 256, 0, stream>>>(dstp, cnt);
    int nb = (NN + SB - 1) / SB;
    k_scan1<<<nb, SB, 0, stream>>>(cnt, rowp, blksum);
    k_scan2<<<1, 128, 0, stream>>>(blksum, blkoff, nb);
    k_scan3<<<(NN + 1 + 255) / 256, 256, 0, stream>>>(rowp, blkoff);
    k_scatter<<<(NE + 255) / 256, 256, 0, stream>>>(srcp, dstp, rowp, fill, cidx);

    int gs = (NN + 255) / 256;           // 512-thread GEMM blocks (256-node tiles)
    int ga = (NN * 32 + 255) / 256;      // k_agg: 32 lanes per node
    // layer 0
    k_agg<<<ga, 256, 0, stream>>>(x, rowp, cidx, bufA);
    k_sage<<<gs, 512, 0, stream>>>(bufA, Wl0, bl0, x, Wr0, bufH);      // h1
    // layer 1
    k_agg<<<ga, 256, 0, stream>>>(bufH, rowp, cidx, bufA);
    k_sage<<<gs, 512, 0, stream>>>(bufA, Wl1, bl1, bufH, Wr1, bufA);   // h2 in-place (wave-owned rows)
    // gate + pool + head
    k_gatef<<<gs, 512, 0, stream>>>(bufA, Wg1, bg1, Wg2, gate);
    k_pstats<<<NG, 256, 0, stream>>>(gate, batch, gm, gden);
    k_pacc<<<(NN + 127) / 128, 256, 0, stream>>>(bufA, gate, batch, gm, gden, gacc);
    k_head<<<NG, 64, 0, stream>>>(gacc, Wh, bh, out);
}